// Round 4
// baseline (718.032 us; speedup 1.0000x reference)
//
#include <hip/hip_runtime.h>
#include <math.h>

#define D    6
#define S    128
#define H    128
#define WIN  16
#define BB   8
#define TT   513
#define NW   32
#define OUTD 10

// ---- device-global scratch ----
__device__ float g_lvl1[BB * NW * D];
__device__ float g_area[BB * NW * D * D];
__device__ float g_h0[BB * S];
__device__ float g_hist[BB * (NW + 1) * S];

__device__ __forceinline__ float sp(float x) {
    return (x > 20.f) ? x : log1pf(expf(x));
}
__device__ __forceinline__ float sigm(float x) {
    return 1.f / (1.f + expf(-x));
}
__device__ __forceinline__ float dot4(float4 a, float4 b, float acc) {
    return fmaf(a.x, b.x, fmaf(a.y, b.y, fmaf(a.z, b.z, fmaf(a.w, b.w, acc))));
}

// ---- LDS layout (float offsets) ----
#define O_W0  0        // [128 r][128 k] row-major (as input)
#define O_W1  16384
#define O_PS  32768    // psum [4 c][6 j][128 r]  (3072) ; aliased psumV [2][768]
#define O_U   35840    // [6][128] tangents U ; later T2
#define O_T   36608    // [6][128] T1 ; later bterm
#define O_V   37376    // [768] V
#define O_H   38144    // h double buffer [2][128]
#define O_U1  38400
#define O_SG1 38528
#define O_U2  38656
#define O_SG2 38784
#define O_B0  38912
#define O_B1  39040
#define O_L1  39168
#define O_AR  39174
#define SMTOT 39216    // 156,864 B

// ---- K2: windowed log-signature + init MLP ----
__global__ __launch_bounds__(256) void k_sig(
        const float* __restrict__ x,
        const float* __restrict__ Wi0, const float* __restrict__ bi0,
        const float* __restrict__ Wi1, const float* __restrict__ bi1,
        const float* __restrict__ Wi2, const float* __restrict__ bi2) {
    const int b = blockIdx.x;
    const int tid = threadIdx.x;
    __shared__ float dxs[NW][WIN][D];
    __shared__ float cums[NW][WIN][D];
    __shared__ float ua[H], ub[H];

    const float* xb = x + (size_t)b * TT * D;

    if (tid < NW * D) {
        int w = tid / D, i = tid % D;
        float run = 0.f;
        float prev = xb[(w * WIN) * D + i];
        for (int k = 0; k < WIN; ++k) {
            float cur = xb[(w * WIN + k + 1) * D + i];
            float d = cur - prev; prev = cur;
            dxs[w][k][i] = d;
            cums[w][k][i] = run;
            run += d;
        }
        g_lvl1[(b * NW + w) * D + i] = run;
    }
    __syncthreads();
    for (int e = tid; e < NW * D * D; e += blockDim.x) {
        int w = e / (D * D); int rem = e % (D * D);
        int i = rem / D, j = rem % D;
        float s = 0.f;
        for (int k = 0; k < WIN; ++k)
            s += cums[w][k][i] * dxs[w][k][j] - cums[w][k][j] * dxs[w][k][i];
        g_area[(b * NW + w) * (D * D) + rem] = 0.5f * s;
    }
    if (tid < H) {
        float z = bi0[tid];
        for (int k = 0; k < D; ++k) z += Wi0[tid * D + k] * xb[k];
        ua[tid] = sp(z);
    }
    __syncthreads();
    if (tid < H) {
        float z = bi1[tid];
        for (int k = 0; k < H; ++k) z += Wi1[tid * H + k] * ua[k];
        ub[tid] = sp(z);
    }
    __syncthreads();
    if (tid < H) {
        float z = bi2[tid];
        for (int k = 0; k < H; ++k) z += Wi2[tid * H + k] * ub[k];
        g_h0[b * S + tid] = z;
    }
}

// ---- K3: the scan ----
__global__ __launch_bounds__(768) void k_scan(
        const float* __restrict__ bv0, const float* __restrict__ bv1,
        const float* __restrict__ bv2,
        const float* __restrict__ Wv0, const float* __restrict__ Wv1,
        const float* __restrict__ Wv2) {
    __shared__ float sm[SMTOT];
    const int b = blockIdx.x, tid = threadIdx.x;
    const int kh = (tid >= 384) ? 1 : 0;      // k-half for W2 stages
    const int m  = tid - kh * 384;            // row-pair index 0..383
    const int rp  = tid & 63;                 // row-pair for W0/W1 stages
    const int c4  = tid >> 6;                 // k-chunk 0..3 (when tid<256)
    const int key = rp & 7;
    const int jj = tid >> 7, rr = tid & 127;  // 6x128 decomposition
    const int j6 = m >> 6;                    // j-block of this thread's W2 rows

    // stage W0, W1 (row-major, verbatim)
    {
        float4* d = (float4*)(sm + O_W0);
        const float4* s0 = (const float4*)Wv0;
        const float4* s1 = (const float4*)Wv1;
        for (int i = tid; i < 4096; i += 768) { d[i] = s0[i]; d[4096 + i] = s1[i]; }
    }
    // W2 row-pair (rows 2m, 2m+1), k-half kh, in registers: 32 float4
    float4 w2e[16], w2o[16];
    {
        const float4* W24 = (const float4*)Wv2;   // [768][32]
        #pragma unroll
        for (int q = 0; q < 16; ++q) {
            w2e[q] = W24[(2 * m) * 32 + kh * 16 + q];
            w2o[q] = W24[(2 * m + 1) * 32 + kh * 16 + q];
        }
    }
    if (tid < 128) {
        sm[O_B0 + tid] = bv0[tid]; sm[O_B1 + tid] = bv1[tid];
        float h0v = g_h0[b * 128 + tid];
        sm[O_H + tid] = h0v;
        g_hist[(b * (NW + 1)) * 128 + tid] = h0v;
    }
    __syncthreads();

    const float4* W04 = (const float4*)(sm + O_W0);
    const float4* W14 = (const float4*)(sm + O_W1);

    int p = 0;
    for (int t = 0; t < NW; ++t) {
        // sig loads (wave 11) — consumed after >=2 barriers
        if (tid >= 704) {
            int q = tid - 704;
            if (q < 6)       sm[O_L1 + q]     = g_lvl1[(b * NW + t) * D + q];
            else if (q < 42) sm[O_AR + q - 6] = g_area[(b * NW + t) * 36 + q - 6];
        }
        // ---- S1: psum[c][0][r] = W0[rows] . h ----
        if (tid < 256) {
            float a0 = 0.f, a1 = 0.f;
            const float4* H4 = (const float4*)(sm + O_H + p * 128);
            #pragma unroll
            for (int q = 0; q < 8; ++q) {
                int qq = c4 * 8 + (q ^ key);
                float4 we = W04[(2 * rp) * 32 + qq];
                float4 wo = W04[(2 * rp + 1) * 32 + qq];
                float4 hv = H4[qq];
                a0 = dot4(we, hv, a0); a1 = dot4(wo, hv, a1);
            }
            *(float2*)&sm[O_PS + (c4 * 6) * 128 + 2 * rp] = make_float2(a0, a1);
        }
        __syncthreads();
        if (tid < 128) {
            float z = sm[O_B0 + tid];
            #pragma unroll
            for (int c = 0; c < 4; ++c) z += sm[O_PS + (c * 6) * 128 + tid];
            sm[O_U1 + tid] = sp(z); sm[O_SG1 + tid] = sigm(z);
        }
        __syncthreads();
        // ---- S2: psum = W1[rows] . u1 ----
        if (tid < 256) {
            float a0 = 0.f, a1 = 0.f;
            const float4* U14 = (const float4*)(sm + O_U1);
            #pragma unroll
            for (int q = 0; q < 8; ++q) {
                int qq = c4 * 8 + (q ^ key);
                float4 we = W14[(2 * rp) * 32 + qq];
                float4 wo = W14[(2 * rp + 1) * 32 + qq];
                float4 hv = U14[qq];
                a0 = dot4(we, hv, a0); a1 = dot4(wo, hv, a1);
            }
            *(float2*)&sm[O_PS + (c4 * 6) * 128 + 2 * rp] = make_float2(a0, a1);
        }
        __syncthreads();
        if (tid < 128) {
            float z = sm[O_B1 + tid];
            #pragma unroll
            for (int c = 0; c < 4; ++c) z += sm[O_PS + (c * 6) * 128 + tid];
            sm[O_U2 + tid] = sp(z); sm[O_SG2 + tid] = sigm(z);
        }
        __syncthreads();
        // ---- S3: psumV[kh][row] = W2rows . u2 (k-half) ----
        {
            float a0 = 0.f, a1 = 0.f;
            const float4* U24 = (const float4*)(sm + O_U2);
            #pragma unroll
            for (int q = 0; q < 16; ++q) {
                float4 u = U24[kh * 16 + q];
                a0 = dot4(w2e[q], u, a0); a1 = dot4(w2o[q], u, a1);
            }
            *(float2*)&sm[O_PS + kh * 768 + 2 * m] = make_float2(a0, a1);
        }
        __syncthreads();
        // ---- R3: V[row] = tanh(sum + b2) ----
        {
            float z = bv2[tid] + sm[O_PS + tid] + sm[O_PS + 768 + tid];
            sm[O_V + tid] = tanhf(z);
        }
        __syncthreads();
        // ---- UF: U[j][r] = sum_i area[i][j] V[i*128+r]; h-next init ----
        {
            float u = 0.f;
            #pragma unroll
            for (int i = 0; i < 6; ++i)
                u = fmaf(sm[O_AR + i * 6 + jj], sm[O_V + i * 128 + rr], u);
            sm[O_U + jj * 128 + rr] = u;
            if (tid < 128) {
                float xh = sm[O_H + p * 128 + tid];
                #pragma unroll
                for (int i = 0; i < 6; ++i)
                    xh = fmaf(sm[O_L1 + i], sm[O_V + i * 128 + tid], xh);
                sm[O_H + (p ^ 1) * 128 + tid] = xh;
            }
        }
        __syncthreads();
        // ---- S4: psum[c][j][r] = W0[rows] . U_j ----
        if (tid < 256) {
            float a0[6] = {0,0,0,0,0,0}, a1[6] = {0,0,0,0,0,0};
            const float4* U4 = (const float4*)(sm + O_U);
            #pragma unroll
            for (int q = 0; q < 8; ++q) {
                int qq = c4 * 8 + (q ^ key);
                float4 we = W04[(2 * rp) * 32 + qq];
                float4 wo = W04[(2 * rp + 1) * 32 + qq];
                #pragma unroll
                for (int j = 0; j < 6; ++j) {
                    float4 u = U4[j * 32 + qq];
                    a0[j] = dot4(we, u, a0[j]); a1[j] = dot4(wo, u, a1[j]);
                }
            }
            #pragma unroll
            for (int j = 0; j < 6; ++j)
                *(float2*)&sm[O_PS + (c4 * 6 + j) * 128 + 2 * rp] = make_float2(a0[j], a1[j]);
        }
        __syncthreads();
        // ---- R4: T1[j][r] = sg1[r] * sum_c ----
        {
            float s = sm[O_PS + jj * 128 + rr] + sm[O_PS + (6 + jj) * 128 + rr]
                    + sm[O_PS + (12 + jj) * 128 + rr] + sm[O_PS + (18 + jj) * 128 + rr];
            sm[O_T + jj * 128 + rr] = sm[O_SG1 + rr] * s;
        }
        __syncthreads();
        // ---- S5: psum[c][j][r] = W1[rows] . T1_j ----
        if (tid < 256) {
            float a0[6] = {0,0,0,0,0,0}, a1[6] = {0,0,0,0,0,0};
            const float4* T4 = (const float4*)(sm + O_T);
            #pragma unroll
            for (int q = 0; q < 8; ++q) {
                int qq = c4 * 8 + (q ^ key);
                float4 we = W14[(2 * rp) * 32 + qq];
                float4 wo = W14[(2 * rp + 1) * 32 + qq];
                #pragma unroll
                for (int j = 0; j < 6; ++j) {
                    float4 u = T4[j * 32 + qq];
                    a0[j] = dot4(we, u, a0[j]); a1[j] = dot4(wo, u, a1[j]);
                }
            }
            #pragma unroll
            for (int j = 0; j < 6; ++j)
                *(float2*)&sm[O_PS + (c4 * 6 + j) * 128 + 2 * rp] = make_float2(a0[j], a1[j]);
        }
        __syncthreads();
        // ---- R5: T2[j][r] = sg2[r] * sum_c  (into O_U) ----
        {
            float s = sm[O_PS + jj * 128 + rr] + sm[O_PS + (6 + jj) * 128 + rr]
                    + sm[O_PS + (12 + jj) * 128 + rr] + sm[O_PS + (18 + jj) * 128 + rr];
            sm[O_U + jj * 128 + rr] = sm[O_SG2 + rr] * s;
        }
        __syncthreads();
        // ---- S6: psumV[kh][row] = W2rows . T2_{j(row)} ----
        {
            float a0 = 0.f, a1 = 0.f;
            const float4* T24 = (const float4*)(sm + O_U);
            #pragma unroll
            for (int q = 0; q < 16; ++q) {
                float4 u = T24[j6 * 32 + kh * 16 + q];
                a0 = dot4(w2e[q], u, a0); a1 = dot4(w2o[q], u, a1);
            }
            *(float2*)&sm[O_PS + kh * 768 + 2 * m] = make_float2(a0, a1);
        }
        __syncthreads();
        // ---- R6: bterm[row] = (1-V^2)*(sum)  (into O_T) ----
        {
            float v = sm[O_V + tid];
            sm[O_T + tid] = (1.f - v * v) * (sm[O_PS + tid] + sm[O_PS + 768 + tid]);
        }
        __syncthreads();
        // ---- H: h update + hist ----
        if (tid < 128) {
            float xh = sm[O_H + (p ^ 1) * 128 + tid];
            #pragma unroll
            for (int j = 0; j < 6; ++j) xh += sm[O_T + j * 128 + tid];
            sm[O_H + (p ^ 1) * 128 + tid] = xh;
            g_hist[(b * (NW + 1) + t + 1) * 128 + tid] = xh;
        }
        p ^= 1;
        __syncthreads();
    }
}

// ---- K4: readout ----
__global__ __launch_bounds__(384) void k_read(const float* __restrict__ Wr,
                                              const float* __restrict__ br,
                                              float* __restrict__ out) {
    const int b = blockIdx.x, e = threadIdx.x;
    if (e < (NW + 1) * OUTD) {
        int t = e / OUTD, o = e % OUTD;
        float z = br[o];
        const float4* hrow = (const float4*)&g_hist[(b * (NW + 1) + t) * 128];
        const float4* wrow = (const float4*)&Wr[o * 128];
        float z0 = 0, z1 = 0, z2 = 0, z3 = 0;
        #pragma unroll 8
        for (int s4 = 0; s4 < 32; ++s4) {
            float4 hv = hrow[s4]; float4 wv = wrow[s4];
            z0 = fmaf(hv.x, wv.x, z0); z1 = fmaf(hv.y, wv.y, z1);
            z2 = fmaf(hv.z, wv.z, z2); z3 = fmaf(hv.w, wv.w, z3);
        }
        out[(b * (NW + 1) + t) * OUTD + o] = z + ((z0 + z1) + (z2 + z3));
    }
}

extern "C" void kernel_launch(void* const* d_in, const int* in_sizes, int n_in,
                              void* d_out, int out_size, void* d_ws, size_t ws_size,
                              hipStream_t stream) {
    const float* x   = (const float*)d_in[0];
    const float* Wi0 = (const float*)d_in[1];
    const float* bi0 = (const float*)d_in[2];
    const float* Wi1 = (const float*)d_in[3];
    const float* bi1 = (const float*)d_in[4];
    const float* Wi2 = (const float*)d_in[5];
    const float* bi2 = (const float*)d_in[6];
    const float* Wv0 = (const float*)d_in[7];
    const float* bv0 = (const float*)d_in[8];
    const float* Wv1 = (const float*)d_in[9];
    const float* bv1 = (const float*)d_in[10];
    const float* Wv2 = (const float*)d_in[11];
    const float* bv2 = (const float*)d_in[12];
    const float* Wr  = (const float*)d_in[13];
    const float* br  = (const float*)d_in[14];
    float* out = (float*)d_out;

    hipLaunchKernelGGL(k_sig,  dim3(BB), dim3(256), 0, stream,
                       x, Wi0, bi0, Wi1, bi1, Wi2, bi2);
    hipLaunchKernelGGL(k_scan, dim3(BB), dim3(768), 0, stream,
                       bv0, bv1, bv2, Wv0, Wv1, Wv2);
    hipLaunchKernelGGL(k_read, dim3(BB), dim3(384), 0, stream, Wr, br, out);
}